// Round 9
// baseline (975.542 us; speedup 1.0000x reference)
//
#include <hip/hip_runtime.h>
#include <hip/hip_bf16.h>
#include <math.h>

// T=10 B=512 N_ALL=23 N_AGENTS=22 NH=8 E=506 RNN_H=64 Z_DIM=92 IN_H=1592
// MFMA heads: K padded 1592->1600 (zero gap f in [184,192)); BN3 folded into
// per-t bf16 weights (Wbt) + epilogue constant (cst). No split-K.
// Pipeline: KA(t)=headsMFMA(t)[32]+edges(t-1)[512]+dec(t-2)[352]
//           KB(t)=gru+zstats(t)[368]+node3(t-1)[46]

typedef __attribute__((ext_vector_type(8))) short s16x8;
typedef __attribute__((ext_vector_type(4))) float f32x4;

__device__ __forceinline__ unsigned short f2bf(float x){
  __hip_bfloat16 b = __float2bfloat16(x);
  return *reinterpret_cast<unsigned short*>(&b);
}
__device__ __forceinline__ float elu_(float x){ return x>0.f ? x : __expf(x)-1.f; }
__device__ __forceinline__ float sp_(float x){ return fmaxf(x,0.f)+log1pf(__expf(-fabsf(x))); }
__device__ __forceinline__ float sig_(float x){ return 1.f/(1.f+__expf(-x)); }
__device__ __forceinline__ float wsum_(float v){
  #pragma unroll
  for (int o=32;o;o>>=1) v += __shfl_down(v,o,64);
  return v;
}

__device__ __forceinline__ void reduce_bn_(const float* __restrict__ part, int n,
    float invN, const float* __restrict__ gam, const float* __restrict__ bet,
    float* sc, float* sh, float* tmp)
{
  int tid = threadIdx.x;
  int c = tid & 15, i0 = tid >> 4;
  float s = 0.f;
  for (int i = i0; i < n; i += 16) s += part[i*16 + c];
  tmp[i0*16 + c] = s;
  __syncthreads();
  if (tid < 16){
    float v = 0.f;
    #pragma unroll
    for (int i=0;i<16;i++) v += tmp[i*16 + tid];
    tmp[tid] = v;
  }
  __syncthreads();
  if (tid < 8){
    float m = tmp[tid]*invN;
    float var = tmp[8+tid]*invN - m*m;
    float rs = rsqrtf(var + 1e-5f);
    float s2 = rs*gam[tid];
    sc[tid] = s2; sh[tid] = bet[tid] - m*s2;
  }
  __syncthreads();
}

__device__ __forceinline__ void block_stats_(const float h[8], float* __restrict__ part,
                                             float red[][16])
{
  int wid = threadIdx.x >> 6, lane = threadIdx.x & 63;
  #pragma unroll
  for (int j=0;j<8;j++){
    float a = wsum_(h[j]);
    float b = wsum_(h[j]*h[j]);
    if (lane==0){ red[wid][j]=a; red[wid][8+j]=b; }
  }
  __syncthreads();
  if (threadIdx.x < 16)
    part[threadIdx.x] = red[0][threadIdx.x]+red[1][threadIdx.x]
                       +red[2][threadIdx.x]+red[3][threadIdx.x];
}

// ================= scan device blocks (256 threads) =================

// MFMA heads: one block = (head, 64-row M-tile); 4 waves x 16 rows; full K.
__device__ __forceinline__ void dev_heads_mfma(
    int idx, int t,
    const unsigned short* __restrict__ g3b,  // [20][512][192] bf16 (pre-BN3)
    const unsigned short* __restrict__ hb,   // [22][512][64]  bf16
    const unsigned short* __restrict__ Wbt,  // [10][4][96][192] bf16 (BN3-scaled)
    const unsigned short* __restrict__ Wbs,  // [4][96][1408] bf16
    const float* __restrict__ cst,           // [10][4][96]
    float* __restrict__ raw)                 // [4][512][92]
{
  int head = idx & 3, mb = idx >> 2;         // mb in [0,8)
  int tid = threadIdx.x;
  int wv = tid >> 6, lane = tid & 63;
  int m0 = mb*64 + wv*16;
  int rloc = lane & 15, kg = lane >> 4;
  int row = m0 + rloc;
  int selg = (head < 2) ? t : 10 + t;
  const unsigned short* Ag = g3b + (size_t)selg*98304 + (size_t)row*192 + kg*8;
  const unsigned short* Wt = Wbt + (size_t)((t*4+head)*96)*192 + kg*8;
  const unsigned short* Wsb = Wbs + (size_t)head*135168;
  f32x4 cd[6];
  #pragma unroll
  for (int n=0;n<6;n++) cd[n] = (f32x4){0.f,0.f,0.f,0.f};
  // region 1: f in [0,192): 6 K-steps (BN3-scaled weights)
  #pragma unroll
  for (int ks=0; ks<6; ks++){
    s16x8 af = *(const s16x8*)(Ag + ks*32);
    #pragma unroll
    for (int n=0;n<6;n++){
      int col = n*16 + rloc;
      s16x8 bf = *(const s16x8*)(Wt + (size_t)col*192 + ks*32);
      cd[n] = __builtin_amdgcn_mfma_f32_16x16x32_bf16(af, bf, cd[n], 0,0,0);
    }
  }
  // region 2: f2 in [0,1408): 44 K-steps (h state)
  const unsigned short* Ah = hb + (size_t)row*64;
  #pragma unroll 4
  for (int ks=0; ks<44; ks++){
    int f2 = ks*32 + kg*8;
    s16x8 af = *(const s16x8*)(Ah + (size_t)(f2>>6)*32768 + (f2&63));
    #pragma unroll
    for (int n=0;n<6;n++){
      int col = n*16 + rloc;
      s16x8 bf = *(const s16x8*)(Wsb + (size_t)col*1408 + f2);
      cd[n] = __builtin_amdgcn_mfma_f32_16x16x32_bf16(af, bf, cd[n], 0,0,0);
    }
  }
  float* dst = raw + (size_t)head*47104;
  const float* cb = cst + (size_t)(t*4+head)*96;
  #pragma unroll
  for (int n=0;n<6;n++){
    int col = n*16 + rloc;
    if (col < 92){
      float cc = cb[col];
      #pragma unroll
      for (int r=0;r<4;r++){
        int rr = m0 + (kg<<2) + r;   // C/D: col=lane&15, row=(lane>>4)*4+reg
        dst[(size_t)rr*92 + col] = cd[n][r] + cc;
      }
    }
  }
}

// edges with inline z (single raw) + KLD. smem 5370 fl.
__device__ __forceinline__ void dev_edges_z(
    float* smem, int b,
    const float* __restrict__ raw_prev, const float* __restrict__ eps_t,
    const float* __restrict__ bpm, const float* __restrict__ bps,
    const float* __restrict__ bem, const float* __restrict__ bes,
    const float* __restrict__ zp1,      // [368][16]
    const float* __restrict__ nW1, const float* __restrict__ nb1,
    const float* __restrict__ nW2, const float* __restrict__ nb2,
    const float* __restrict__ g1, const float* __restrict__ bt1,
    const float* __restrict__ eW1, const float* __restrict__ eb1,
    const float* __restrict__ eW2, const float* __restrict__ eb2,
    float* __restrict__ zna, float* __restrict__ zp2, float* __restrict__ lklp_t)
{
  int tid = threadIdx.x;
  float* tmp   = smem;        // 256
  float* sc1   = smem+256;    // 8
  float* sh1   = smem+264;    // 8
  float* xnode = smem+272;    // 207
  float* accs  = smem+480;    // 207
  float* redsq = smem+688;    // 32
  float* zrow  = smem+720;    // 92
  float* redk  = smem+812;    // 4
  float* le    = smem+816;    // 4554
  { // BN1 reduce over 368 partials
    int c = tid & 15, i0 = tid >> 4;
    float s = 0.f;
    for (int i=i0;i<368;i+=16) s += zp1[i*16+c];
    tmp[i0*16+c] = s;
    __syncthreads();
    if (tid<16){
      float v=0.f;
      #pragma unroll
      for (int i=0;i<16;i++) v += tmp[i*16+tid];
      tmp[tid]=v;
    }
    __syncthreads();
    if (tid<8){
      float m = tmp[tid]*(1.f/11776.f);
      float var = tmp[8+tid]*(1.f/11776.f) - m*m;
      float rs = rsqrtf(var+1e-5f);
      float s2 = rs*g1[tid];
      sc1[tid]=s2; sh1[tid]=bt1[tid]-m*s2;
    }
  }
  float kld = 0.f;
  if (tid < 92){
    int j = tid;
    const float* q = raw_prev + (size_t)b*92 + j;
    float pm = bpm[j] + q[0];
    float ps = sp_(bps[j] + q[47104]);
    float em = bem[j] + q[94208];
    float es = sp_(bes[j] + q[141312]);
    float z = em + es*eps_t[(size_t)b*92 + j];
    zrow[j] = z;
    float d = em - pm;
    kld = 0.5f*(2.f*logf(ps/es) + (es*es + d*d)/(ps*ps) - 1.f);
  }
  float kv = wsum_(kld);
  if ((tid&63)==0) redk[tid>>6] = kv;
  __syncthreads();
  if (tid==0) lklp_t[b] = redk[0]+redk[1]+redk[2]+redk[3];
  if (tid < 23){
    float z0=zrow[tid*4], z1=zrow[tid*4+1], z2=zrow[tid*4+2], z3=zrow[tid*4+3];
    float h1[8];
    #pragma unroll
    for (int j=0;j<8;j++)
      h1[j] = elu_(nb1[j] + nW1[j*4]*z0 + nW1[j*4+1]*z1 + nW1[j*4+2]*z2 + nW1[j*4+3]*z3);
    #pragma unroll
    for (int j=0;j<8;j++){
      float a = nb2[j];
      #pragma unroll
      for (int k=0;k<8;k++) a += nW2[j*8+k]*h1[k];
      xnode[tid*9+j] = elu_(a)*sc1[j] + sh1[j];
    }
  }
  __syncthreads();
  float sq[8]={0,0,0,0,0,0,0,0};
  for (int e=tid; e<506; e+=256){
    int r=e/22, jj=e-r*22;
    int s=jj+(jj>=r?1:0);
    float et0=(jj==0 && r>=1 && r<=21)?1.f:0.f;
    float et1=(r==22)?1.f:0.f;
    float h1[8];
    #pragma unroll
    for (int j=0;j<8;j++){
      const float* w=eW1+j*18;
      float a=eb1[j]+w[16]*et0+w[17]*et1;
      #pragma unroll
      for (int k=0;k<8;k++) a+=w[k]*xnode[s*9+k];
      #pragma unroll
      for (int k=0;k<8;k++) a+=w[8+k]*xnode[r*9+k];
      h1[j]=elu_(a);
    }
    #pragma unroll
    for (int j=0;j<8;j++){
      float a=eb2[j];
      #pragma unroll
      for (int k=0;k<8;k++) a+=eW2[j*8+k]*h1[k];
      float h2=elu_(a);
      le[e*9+j]=h2;
      sq[j]+=h2*h2;
    }
  }
  int wid=tid>>6, lane=tid&63;
  #pragma unroll
  for (int j=0;j<8;j++){
    float v=wsum_(sq[j]);
    if (lane==0) redsq[wid*8+j]=v;
  }
  __syncthreads();
  if (tid<184){
    int r=tid>>3, c=tid&7;
    const float* lp = le + r*198 + c;
    float s=0.f;
    #pragma unroll
    for (int jj=0;jj<22;jj++) s+=lp[jj*9];
    accs[r*9+c]=s;
    zna[(size_t)b*184+tid]=s;
  }
  __syncthreads();
  if (tid<16){
    int c=tid&7;
    float s=0.f;
    if (tid<8){
      #pragma unroll
      for (int r=0;r<23;r++) s+=accs[r*9+c];
    } else {
      #pragma unroll
      for (int w=0;w<4;w++) s+=redsq[w*8+c];
    }
    zp2[(size_t)b*16+tid]=s;
  }
}

// node3 (smem 336 fl); writes fp32 (scan, outf) or bf16 (precompute, outb)
__device__ __forceinline__ void dev_node3(
    float* smem, int bi, int g, int p,
    const float* __restrict__ nodeacc, const float* __restrict__ p2,
    const float* __restrict__ g2b, const float* __restrict__ bt2b,
    const float* __restrict__ W3b, const float* __restrict__ b3b,
    const float* __restrict__ W4b, const float* __restrict__ b4b,
    float* __restrict__ outf, unsigned short* __restrict__ outb,
    float* __restrict__ p3)
{
  float* tmp = smem; float* sc2 = smem+256; float* sh2 = smem+264;
  float (*red)[16] = (float(*)[16])(smem+272);
  reduce_bn_(p2 + (size_t)g*8192, 512, 1.f/259072.f, g2b+p*8, bt2b+p*8, sc2, sh2, tmp);
  int row = bi*256 + threadIdx.x;
  int b = row/23, r = row - b*23;
  const float inv23 = 1.f/23.f;
  const float* na = nodeacc + ((size_t)g*512 + b)*184 + r*8;
  float xk[8];
  #pragma unroll
  for (int k=0;k<8;k++) xk[k] = (na[k]*sc2[k] + 22.f*sh2[k]) * inv23;
  float nt0 = (r<22)?inv23:0.f, nt1 = (r==22)?inv23:0.f;
  const float* W3 = W3b + p*80; const float* b3 = b3b + p*8;
  const float* W4 = W4b + p*64; const float* b4 = b4b + p*8;
  float h1b[8], o[8];
  #pragma unroll
  for (int j=0;j<8;j++){
    const float* w = W3 + j*10;
    float a = b3[j] + w[8]*nt0 + w[9]*nt1;
    #pragma unroll
    for (int k=0;k<8;k++) a += w[k]*xk[k];
    h1b[j] = elu_(a);
  }
  #pragma unroll
  for (int j=0;j<8;j++){
    float a = b4[j];
    #pragma unroll
    for (int k=0;k<8;k++) a += W4[j*8+k]*h1b[k];
    o[j] = elu_(a);
    if (outf) outf[(size_t)row*8 + j] = o[j];
    else outb[(size_t)g*98304 + (size_t)b*192 + r*8 + j] = f2bf(o[j]);
  }
  block_stats_(o, p3 + ((size_t)g*46 + bi)*16, red);
}

// dec (smem 520 fl)
__device__ __forceinline__ void dev_dec(
    float* smem, int bi,
    const float* __restrict__ zg3, const float* __restrict__ p3,
    const float* __restrict__ gam, const float* __restrict__ bet,
    const float* __restrict__ Wm, const float* __restrict__ Bm,
    const float* __restrict__ Wsd, const float* __restrict__ Bsd,
    float* __restrict__ odm, float* __restrict__ ods)
{
  int tid = threadIdx.x;
  float* dtmp = smem; float* dsc = smem + 256; float* dsh = smem + 264;
  reduce_bn_(p3, 46, 1.f/11776.f, gam, bet, dsc, dsh, dtmp);
  float4 s0 = {dsc[0],dsc[1],dsc[2],dsc[3]};
  float4 s1 = {dsc[4],dsc[5],dsc[6],dsc[7]};
  float4 t0 = {dsh[0],dsh[1],dsh[2],dsh[3]};
  float4 t1 = {dsh[4],dsh[5],dsh[6],dsh[7]};
  int idx = bi*256 + tid;
  int hd = idx / 45056; int rem = idx - hd*45056;
  int b = rem / 88, j = rem - b*88;
  const float* W = hd ? Wsd : Wm;
  const float4* a4 = (const float4*)(zg3 + (size_t)b*184);
  const float4* w4 = (const float4*)(W + (size_t)j*184);
  float accv = hd ? Bsd[j] : Bm[j];
  #pragma unroll 2
  for (int i4=0;i4<46;i4++){
    float4 x = a4[i4]; float4 w = w4[i4];
    float4 sc = (i4&1)? s1 : s0; float4 sh = (i4&1)? t1 : t0;
    accv += w.x*(x.x*sc.x+sh.x) + w.y*(x.y*sc.y+sh.y)
          + w.z*(x.z*sc.z+sh.z) + w.w*(x.w*sc.w+sh.w);
  }
  if (hd) ods[(size_t)b*88+j] = sp_(accv);
  else    odm[(size_t)b*88+j] = accv;
}

// gru with inline z (single raw) + z-node MLP1 stats + bf16 h copy. smem 14944.
__device__ __forceinline__ void dev_gru_z(
    float* smem, int idx,
    float* __restrict__ h, unsigned short* __restrict__ hbf,
    const float* __restrict__ x_t,
    const float* __restrict__ raw_cur, const float* __restrict__ eps_t,
    const float* __restrict__ bem, const float* __restrict__ bes,
    const float* __restrict__ nW1, const float* __restrict__ nb1,
    const float* __restrict__ nW2, const float* __restrict__ nb2,
    float* __restrict__ zp1,
    const float* __restrict__ Wih, const float* __restrict__ Whh,
    const float* __restrict__ bih, const float* __restrict__ bhh)
{
  int tid = threadIdx.x;
  float* WhT  = smem;           // 64*193 = 12352
  float* hs   = smem + 12352;   // 64*36  = 2304
  float* gins = smem + 14656;   // 8*36   = 288
  int a = idx >> 4, yb = idx & 15;
  int b0 = yb*32;
  int c = tid & 63, sq = tid >> 6;
  const float* Wg = Whh + (size_t)a*12288;
  for (int e = tid; e < 12288; e += 256) WhT[(e&63)*193 + (e>>6)] = Wg[e];
  const float* hp_g = h + (size_t)a*32768 + (size_t)b0*64;
  for (int e = tid; e < 2048; e += 256) hs[(e&63)*36 + (e>>6)] = hp_g[e];
  { int s = tid >> 3, k = tid & 7;
    float v;
    if (k < 4) v = x_t[(size_t)(b0+s)*92 + a*4 + k];
    else {
      int j = a*4 + (k-4);
      float em = bem[j] + raw_cur[94208 + (size_t)(b0+s)*92 + j];
      float es = sp_(bes[j] + raw_cur[141312 + (size_t)(b0+s)*92 + j]);
      v = em + es*eps_t[(size_t)(b0+s)*92 + j];
    }
    gins[k*36 + s] = v; }
  float wi0[8], wi1[8], wi2[8];
  const float* Wig = Wih + (size_t)a*1536;
  #pragma unroll
  for (int k=0;k<8;k++){
    wi0[k] = Wig[c*8+k]; wi1[k] = Wig[(64+c)*8+k]; wi2[k] = Wig[(128+c)*8+k];
  }
  float bi0 = bih[a*192+c], bi1 = bih[a*192+64+c], bi2 = bih[a*192+128+c];
  float bh0 = bhh[a*192+c], bh1 = bhh[a*192+64+c], bh2 = bhh[a*192+128+c];
  __syncthreads();
  { // z-node MLP1 stats (threads 0..31)
    float h2s[8];
    if (tid < 32){
      float z0=gins[4*36+tid], z1=gins[5*36+tid], z2=gins[6*36+tid], z3=gins[7*36+tid];
      float h1s[8];
      #pragma unroll
      for (int j=0;j<8;j++)
        h1s[j] = elu_(nb1[j] + nW1[j*4]*z0 + nW1[j*4+1]*z1 + nW1[j*4+2]*z2 + nW1[j*4+3]*z3);
      #pragma unroll
      for (int j=0;j<8;j++){
        float av = nb2[j];
        #pragma unroll
        for (int k=0;k<8;k++) av += nW2[j*8+k]*h1s[k];
        h2s[j] = elu_(av);
      }
    } else {
      #pragma unroll
      for (int j=0;j<8;j++) h2s[j] = 0.f;
    }
    float* dst = zp1 + (size_t)(a*16+yb)*16;
    #pragma unroll
    for (int j=0;j<8;j++){
      float s1 = wsum_(h2s[j]);
      float s2 = wsum_(h2s[j]*h2s[j]);
      if (tid==0){ dst[j]=s1; dst[8+j]=s2; }
    }
  }
  #pragma unroll
  for (int ps=0; ps<2; ps++){
    int s0 = ps*16 + sq*4;
    float q0[4], q1[4], q2[4];
    #pragma unroll
    for (int i=0;i<4;i++){ q0[i]=bh0; q1[i]=bh1; q2[i]=bh2; }
    for (int k=0;k<64;k++){
      float w0 = WhT[k*193 + c];
      float w1 = WhT[k*193 + 64 + c];
      float w2 = WhT[k*193 + 128 + c];
      float4 hv = *(const float4*)&hs[k*36 + s0];
      float hvv[4] = {hv.x,hv.y,hv.z,hv.w};
      #pragma unroll
      for (int i=0;i<4;i++){ q0[i]+=w0*hvv[i]; q1[i]+=w1*hvv[i]; q2[i]+=w2*hvv[i]; }
    }
    float g0[4], g1[4], g2[4];
    #pragma unroll
    for (int i=0;i<4;i++){ g0[i]=bi0; g1[i]=bi1; g2[i]=bi2; }
    #pragma unroll
    for (int k=0;k<8;k++){
      float4 gv = *(const float4*)&gins[k*36 + s0];
      float gvv[4] = {gv.x,gv.y,gv.z,gv.w};
      #pragma unroll
      for (int i=0;i<4;i++){ g0[i]+=wi0[k]*gvv[i]; g1[i]+=wi1[k]*gvv[i]; g2[i]+=wi2[k]*gvv[i]; }
    }
    float4 hp = *(const float4*)&hs[c*36 + s0];
    float hpv[4] = {hp.x,hp.y,hp.z,hp.w};
    #pragma unroll
    for (int i=0;i<4;i++){
      float rg = sig_(g0[i]+q0[i]);
      float zg = sig_(g1[i]+q1[i]);
      float ng = tanhf(g2[i] + rg*q2[i]);
      float hn = (1.f-zg)*ng + zg*hpv[i];
      size_t off = (size_t)a*32768 + (size_t)(b0+s0+i)*64 + c;
      h[off] = hn;
      hbf[off] = f2bf(hn);
    }
  }
}

// node-22 z MLP1 stats
__device__ __forceinline__ void dev_z22(
    int yb,
    const float* __restrict__ raw_cur, const float* __restrict__ eps_t,
    const float* __restrict__ bem, const float* __restrict__ bes,
    const float* __restrict__ nW1, const float* __restrict__ nb1,
    const float* __restrict__ nW2, const float* __restrict__ nb2,
    float* __restrict__ zp1)
{
  int tid = threadIdx.x;
  int b0 = yb*32;
  float h2s[8];
  if (tid < 32){
    float zv[4];
    #pragma unroll
    for (int q=0;q<4;q++){
      int j = 88+q;
      float em = bem[j] + raw_cur[94208 + (size_t)(b0+tid)*92 + j];
      float es = sp_(bes[j] + raw_cur[141312 + (size_t)(b0+tid)*92 + j]);
      zv[q] = em + es*eps_t[(size_t)(b0+tid)*92 + j];
    }
    float h1s[8];
    #pragma unroll
    for (int j=0;j<8;j++)
      h1s[j] = elu_(nb1[j] + nW1[j*4]*zv[0] + nW1[j*4+1]*zv[1] + nW1[j*4+2]*zv[2] + nW1[j*4+3]*zv[3]);
    #pragma unroll
    for (int j=0;j<8;j++){
      float av = nb2[j];
      #pragma unroll
      for (int k=0;k<8;k++) av += nW2[j*8+k]*h1s[k];
      h2s[j] = elu_(av);
    }
  } else {
    #pragma unroll
    for (int j=0;j<8;j++) h2s[j] = 0.f;
  }
  float* dst = zp1 + (size_t)(352+yb)*16;
  #pragma unroll
  for (int j=0;j<8;j++){
    float s1 = wsum_(h2s[j]);
    float s2 = wsum_(h2s[j]*h2s[j]);
    if (tid==0){ dst[j]=s1; dst[8+j]=s2; }
  }
}

// ================= precompute kernels =================

__global__ __launch_bounds__(256) void k_stats1(
    const float* __restrict__ states,
    const float* __restrict__ W1b, const float* __restrict__ b1b,
    const float* __restrict__ W2b, const float* __restrict__ b2b,
    float* __restrict__ part)
{
  int g = blockIdx.y; int p = g/10; int t = g - p*10;
  const float* W1 = W1b + p*32; const float* b1 = b1b + p*8;
  const float* W2 = W2b + p*64; const float* b2 = b2b + p*8;
  int row = blockIdx.x*256 + threadIdx.x;
  float4 x4 = *(const float4*)(states + (size_t)(t+p)*47104 + 4*(size_t)row);
  float h1[8], h2[8];
  #pragma unroll
  for (int j=0;j<8;j++)
    h1[j] = elu_(b1[j] + W1[j*4+0]*x4.x + W1[j*4+1]*x4.y + W1[j*4+2]*x4.z + W1[j*4+3]*x4.w);
  #pragma unroll
  for (int j=0;j<8;j++){
    float a = b2[j];
    #pragma unroll
    for (int k=0;k<8;k++) a += W2[j*8+k]*h1[k];
    h2[j] = elu_(a);
  }
  __shared__ float red[4][16];
  block_stats_(h2, part + ((size_t)g*46 + blockIdx.x)*16, red);
}

__global__ __launch_bounds__(512) void k_pre_edges(
    const float* __restrict__ src, const float* __restrict__ p1,
    const float* __restrict__ nW1b, const float* __restrict__ nb1b,
    const float* __restrict__ nW2b, const float* __restrict__ nb2b,
    const float* __restrict__ g1b, const float* __restrict__ bt1b,
    const float* __restrict__ eW1b, const float* __restrict__ eb1b,
    const float* __restrict__ eW2b, const float* __restrict__ eb2b,
    float* __restrict__ nodeacc, float* __restrict__ p2)
{
  int g = blockIdx.y; int p = g/10; int t = g - p*10; int b = blockIdx.x;
  int tid = threadIdx.x;
  __shared__ float tmp[512];
  __shared__ float sc1[8], sh1[8];
  __shared__ float xnode[207];
  __shared__ float le[4554];
  __shared__ float accs[207];
  __shared__ float redsq[8][8];
  {
    const float* pp = p1 + (size_t)g*736;
    int c = tid & 15, i0 = tid >> 4;
    float s = 0.f;
    for (int i = i0; i < 46; i += 32) s += pp[i*16 + c];
    tmp[i0*16 + c] = s;
    __syncthreads();
    if (tid < 16){
      float v = 0.f;
      #pragma unroll
      for (int i=0;i<32;i++) v += tmp[i*16 + tid];
      tmp[tid] = v;
    }
    __syncthreads();
    if (tid < 8){
      float m = tmp[tid]*(1.f/11776.f);
      float var = tmp[8+tid]*(1.f/11776.f) - m*m;
      float rs = rsqrtf(var + 1e-5f);
      float s2 = rs*g1b[p*8+tid];
      sc1[tid] = s2; sh1[tid] = bt1b[p*8+tid] - m*s2;
    }
    __syncthreads();
  }
  if (tid < 23){
    const float* x = src + (size_t)(t+p)*47104 + (size_t)b*92 + tid*4;
    const float* W1 = nW1b + p*32; const float* b1 = nb1b + p*8;
    const float* W2 = nW2b + p*64; const float* b2 = nb2b + p*8;
    float x0=x[0], x1=x[1], x2=x[2], x3=x[3];
    float h1[8];
    #pragma unroll
    for (int j=0;j<8;j++)
      h1[j] = elu_(b1[j] + W1[j*4]*x0 + W1[j*4+1]*x1 + W1[j*4+2]*x2 + W1[j*4+3]*x3);
    #pragma unroll
    for (int j=0;j<8;j++){
      float a = b2[j];
      #pragma unroll
      for (int k=0;k<8;k++) a += W2[j*8+k]*h1[k];
      xnode[tid*9+j] = elu_(a)*sc1[j] + sh1[j];
    }
  }
  __syncthreads();
  float sq[8] = {0,0,0,0,0,0,0,0};
  if (tid < 506){
    int r = tid/22, jj = tid - r*22;
    int s = jj + (jj>=r ? 1 : 0);
    const float* W1 = eW1b + p*144; const float* b1 = eb1b + p*8;
    const float* W2 = eW2b + p*64;  const float* b2 = eb2b + p*8;
    float et0 = (jj==0 && r>=1 && r<=21) ? 1.f : 0.f;
    float et1 = (r==22) ? 1.f : 0.f;
    float h1[8];
    #pragma unroll
    for (int j=0;j<8;j++){
      const float* w = W1 + j*18;
      float a = b1[j] + w[16]*et0 + w[17]*et1;
      #pragma unroll
      for (int k=0;k<8;k++) a += w[k]*xnode[s*9+k];
      #pragma unroll
      for (int k=0;k<8;k++) a += w[8+k]*xnode[r*9+k];
      h1[j] = elu_(a);
    }
    #pragma unroll
    for (int j=0;j<8;j++){
      float a = b2[j];
      #pragma unroll
      for (int k=0;k<8;k++) a += W2[j*8+k]*h1[k];
      float h2 = elu_(a);
      le[tid*9+j] = h2;
      sq[j] = h2*h2;
    }
  }
  int wid = tid >> 6, lane = tid & 63;
  #pragma unroll
  for (int j=0;j<8;j++){
    float v = wsum_(sq[j]);
    if (lane==0) redsq[wid][j] = v;
  }
  __syncthreads();
  if (tid < 184){
    int r = tid >> 3, c = tid & 7;
    const float* lp = le + r*198 + c;
    float s = 0.f;
    #pragma unroll
    for (int jj=0;jj<22;jj++) s += lp[jj*9];
    accs[r*9+c] = s;
    nodeacc[((size_t)g*512 + b)*184 + tid] = s;
  }
  __syncthreads();
  if (tid < 16){
    int c = tid & 7;
    float s = 0.f;
    if (tid < 8){
      #pragma unroll
      for (int r=0;r<23;r++) s += accs[r*9+c];
    } else {
      #pragma unroll
      for (int w=0;w<8;w++) s += redsq[w][c];
    }
    p2[((size_t)g*512 + b)*16 + tid] = s;
  }
}

__global__ __launch_bounds__(256) void k_pre_node3(
    const float* __restrict__ nodeacc, const float* __restrict__ p2,
    const float* __restrict__ g2, const float* __restrict__ bt2,
    const float* __restrict__ W3, const float* __restrict__ b3,
    const float* __restrict__ W4, const float* __restrict__ b4,
    unsigned short* __restrict__ g3b, float* __restrict__ p3)
{
  __shared__ float smem[336];
  int g = blockIdx.y, p = g/10;
  dev_node3(smem, blockIdx.x, g, p, nodeacc, p2, g2, bt2, W3,b3,W4,b4,
            nullptr, g3b, p3);
}

__global__ __launch_bounds__(256) void k_bnred(
    const float* __restrict__ part, int n, float invN,
    const float* __restrict__ gamb, const float* __restrict__ betb,
    float* __restrict__ scsh)
{
  int g = blockIdx.x; int p = g/10;
  int tid = threadIdx.x;
  __shared__ float tmp[256];
  const float* pp = part + (size_t)g*n*16;
  int c = tid & 15, i0 = tid >> 4;
  float s = 0.f;
  for (int i = i0; i < n; i += 16) s += pp[i*16 + c];
  tmp[i0*16 + c] = s;
  __syncthreads();
  if (tid < 16){
    float v = 0.f;
    #pragma unroll
    for (int i=0;i<16;i++) v += tmp[i*16 + tid];
    tmp[tid] = v;
  }
  __syncthreads();
  if (tid < 8){
    float m = tmp[tid]*invN;
    float var = tmp[8+tid]*invN - m*m;
    float rs = rsqrtf(var + 1e-5f);
    float sc = rs*gamb[p*8+tid];
    scsh[g*16 + tid] = sc;
    scsh[g*16 + 8 + tid] = betb[p*8+tid] - m*sc;
  }
}

__global__ __launch_bounds__(256) void k_wbs(
    const float* __restrict__ Wpm, const float* __restrict__ Wps,
    const float* __restrict__ Wem, const float* __restrict__ Wes,
    unsigned short* __restrict__ Wbs)
{
  int e = blockIdx.x*256 + threadIdx.x;       // [0, 540672)
  int head = e / 135168; int rem = e - head*135168;
  int col = rem / 1408; int f2 = rem - col*1408;
  const float* W = (head==0)?Wpm:(head==1)?Wps:(head==2)?Wem:Wes;
  float v = (col<92) ? W[(size_t)col*1592 + 184 + f2] : 0.f;
  Wbs[e] = f2bf(v);
}

__global__ __launch_bounds__(256) void k_wbt(
    const float* __restrict__ Wpm, const float* __restrict__ Wps,
    const float* __restrict__ Wem, const float* __restrict__ Wes,
    const float* __restrict__ scsh3,
    unsigned short* __restrict__ Wbt)
{
  int e = blockIdx.x*256 + threadIdx.x;       // [0, 737280)
  int t = e / 73728; int rem = e - t*73728;
  int head = rem / 18432; int rem2 = rem - head*18432;
  int col = rem2 / 192; int f = rem2 - col*192;
  const float* W = (head==0)?Wpm:(head==1)?Wps:(head==2)?Wem:Wes;
  int sel = (head<2) ? t : 10+t;
  float v = (col<92 && f<184) ? W[(size_t)col*1592 + f]*scsh3[sel*16 + (f&7)] : 0.f;
  Wbt[e] = f2bf(v);
}

__global__ __launch_bounds__(256) void k_cst(
    const float* __restrict__ Wpm, const float* __restrict__ Wps,
    const float* __restrict__ Wem, const float* __restrict__ Wes,
    const float* __restrict__ scsh3, float* __restrict__ cst)
{
  int e = blockIdx.x*256 + threadIdx.x;      // [0, 3840)
  if (e >= 3840) return;
  int t = e / 384; int rem = e - t*384;
  int head = rem / 96; int col = rem - head*96;
  float s = 0.f;
  if (col < 92){
    const float* W = (head==0)?Wpm:(head==1)?Wps:(head==2)?Wem:Wes;
    int sel = (head<2) ? t : 10+t;
    const float* sh = scsh3 + sel*16 + 8;
    for (int f=0; f<184; f++) s += W[(size_t)col*1592+f]*sh[f&7];
  }
  cst[e] = s;
}

// ================= scan kernels =================

__global__ __launch_bounds__(256) void k_KA(
    int nh, int ne, int t,
    const unsigned short* __restrict__ g3b, const unsigned short* __restrict__ hbf,
    const unsigned short* __restrict__ Wbt, const unsigned short* __restrict__ Wbs,
    const float* __restrict__ cst, float* __restrict__ raw_cur,
    const float* __restrict__ raw_prev, const float* __restrict__ eps_prev,
    const float* __restrict__ bpm, const float* __restrict__ bps,
    const float* __restrict__ bem, const float* __restrict__ bes,
    const float* __restrict__ zp1,
    const float* __restrict__ nW1, const float* __restrict__ nb1,
    const float* __restrict__ nW2, const float* __restrict__ nb2,
    const float* __restrict__ g1, const float* __restrict__ bt1,
    const float* __restrict__ eW1, const float* __restrict__ eb1,
    const float* __restrict__ eW2, const float* __restrict__ eb2,
    float* __restrict__ zna, float* __restrict__ zp2, float* __restrict__ lklp_t,
    const float* __restrict__ zg3, const float* __restrict__ zp3,
    const float* __restrict__ gam3, const float* __restrict__ bet3,
    const float* __restrict__ Wm, const float* __restrict__ Bm,
    const float* __restrict__ Wsd, const float* __restrict__ Bsd,
    float* __restrict__ odm, float* __restrict__ ods)
{
  __shared__ float smem[5370];
  int it = blockIdx.x;
  if (it < nh)
    dev_heads_mfma(it, t, g3b, hbf, Wbt, Wbs, cst, raw_cur);
  else if (it < nh+ne)
    dev_edges_z(smem, it-nh, raw_prev, eps_prev, bpm,bps,bem,bes, zp1,
                nW1,nb1,nW2,nb2, g1,bt1, eW1,eb1,eW2,eb2, zna, zp2, lklp_t);
  else
    dev_dec(smem, it-nh-ne, zg3, zp3, gam3, bet3, Wm,Bm,Wsd,Bsd, odm, ods);
}

__global__ __launch_bounds__(256) void k_KB(
    int ng,
    float* __restrict__ h, unsigned short* __restrict__ hbf,
    const float* __restrict__ x_t,
    const float* __restrict__ raw_cur, const float* __restrict__ eps_t,
    const float* __restrict__ bem, const float* __restrict__ bes,
    const float* __restrict__ nW1, const float* __restrict__ nb1,
    const float* __restrict__ nW2, const float* __restrict__ nb2,
    float* __restrict__ zp1,
    const float* __restrict__ Wih, const float* __restrict__ Whh,
    const float* __restrict__ bih, const float* __restrict__ bhh,
    const float* __restrict__ zna, const float* __restrict__ zp2,
    const float* __restrict__ g2, const float* __restrict__ bt2,
    const float* __restrict__ W3, const float* __restrict__ b3,
    const float* __restrict__ W4, const float* __restrict__ b4,
    float* __restrict__ zg3, float* __restrict__ zp3)
{
  __shared__ float smem[14944];
  int it = blockIdx.x;
  if (it < ng){
    if (it < ng-16)
      dev_gru_z(smem, it, h, hbf, x_t, raw_cur, eps_t, bem, bes,
                nW1,nb1,nW2,nb2, zp1, Wih, Whh, bih, bhh);
    else
      dev_z22(it-(ng-16), raw_cur, eps_t, bem, bes, nW1,nb1,nW2,nb2, zp1);
  } else
    dev_node3(smem, it-ng, 0, 0, zna, zp2, g2, bt2, W3,b3,W4,b4,
              zg3, nullptr, zp3);
}

__global__ __launch_bounds__(256) void k_final(const float* __restrict__ lklp,
                                               float* __restrict__ out){
  __shared__ float red[4];
  float s = 0.f;
  for (int i = threadIdx.x; i < 5120; i += 256) s += lklp[i];
  s = wsum_(s);
  if ((threadIdx.x&63)==0) red[threadIdx.x>>6]=s;
  __syncthreads();
  if (threadIdx.x==0) out[0] = red[0]+red[1]+red[2]+red[3];
}

extern "C" void kernel_launch(void* const* d_in, const int* in_sizes, int n_in,
                              void* d_out, int out_size, void* d_ws, size_t ws_size,
                              hipStream_t stream)
{
  (void)in_sizes; (void)n_in; (void)out_size; (void)ws_size;
  const float* states=(const float*)d_in[0];
  const float* eps   =(const float*)d_in[1];
  const float *m1W1=(const float*)d_in[2],  *m1b1=(const float*)d_in[3],
              *m1W2=(const float*)d_in[4],  *m1b2=(const float*)d_in[5],
              *m1g =(const float*)d_in[6],  *m1bt=(const float*)d_in[7];
  const float *m2W1=(const float*)d_in[8],  *m2b1=(const float*)d_in[9],
              *m2W2=(const float*)d_in[10], *m2b2=(const float*)d_in[11],
              *m2g =(const float*)d_in[12], *m2bt=(const float*)d_in[13];
  const float *m3W1=(const float*)d_in[14], *m3b1=(const float*)d_in[15],
              *m3W2=(const float*)d_in[16], *m3b2=(const float*)d_in[17],
              *m3g =(const float*)d_in[18], *m3bt=(const float*)d_in[19];
  const float *emW=(const float*)d_in[20], *emB=(const float*)d_in[21];
  const float *esW=(const float*)d_in[22], *esB=(const float*)d_in[23];
  const float *pmW=(const float*)d_in[24], *pmB=(const float*)d_in[25];
  const float *psW=(const float*)d_in[26], *psB=(const float*)d_in[27];
  const float *dmW=(const float*)d_in[28], *dmB=(const float*)d_in[29];
  const float *dsW=(const float*)d_in[30], *dsB=(const float*)d_in[31];
  const float *gWih=(const float*)d_in[32], *gWhh=(const float*)d_in[33];
  const float *gbih=(const float*)d_in[34], *gbhh=(const float*)d_in[35];
  float* out = (float*)d_out;
  float* ws  = (float*)d_ws;

  // layout (float offsets); bf16 buffers at 16B-aligned offsets
  unsigned short* g3b = (unsigned short*)(ws);            // [20][512][192] bf16 = 983,040 fl
  unsigned short* Wbt = (unsigned short*)(ws + 983040);   // [10][4][96][192] = 368,640 fl
  unsigned short* Wbs = (unsigned short*)(ws + 1351680);  // [4][96][1408]   = 270,336 fl
  unsigned short* hbf = (unsigned short*)(ws + 1622016);  // [22][512][64]   = 360,448 fl
  float* h     = ws + 1982464;       // 720,896
  float* cst   = ws + 2703360;       // 3,840
  float* scsh3 = ws + 2707200;       // 320
  float* lklp  = ws + 2707520;       // 5,120
  float* zp1   = ws + 2712640;       // 5,888
  float* zna   = ws + 2718528;       // 94,208
  float* zp2   = ws + 2812736;       // 8,192
  float* zg3   = ws + 2820928;       // 94,208
  float* zp3   = ws + 2915136;       // 736
  float* raw0  = ws + 2915872;       // [4][512][92] = 188,416
  float* raw1  = ws + 3104288;       // 188,416
  float* scr   = ws + 3292704;       // precompute scratch
  float* p1p = scr;                  // 14,720
  float* naP = scr + 14720;          // 1,884,160
  float* p2p = scr + 1898880;        // 163,840
  float* p3p = scr + 2062720;        // 14,720
  // total = 3,292,704 + 2,077,440 = 5,370,144 fl = 21.5 MB

  hipMemsetAsync(h, 0, 720896*sizeof(float), stream);
  hipMemsetAsync(hbf, 0, 720896*sizeof(unsigned short), stream);
  hipMemsetAsync(g3b, 0, 1966080*sizeof(unsigned short), stream);

  // ---- precompute gnn(y,p=0)/gnn(x,p=1), all t (g = p*10+t) ----
  k_stats1<<<dim3(46,20),256,0,stream>>>(states, m1W1, m1b1, m1W2, m1b2, p1p);
  k_pre_edges<<<dim3(512,20),512,0,stream>>>(states, p1p,
      m1W1, m1b1, m1W2, m1b2, m1g, m1bt,
      m2W1, m2b1, m2W2, m2b2, naP, p2p);
  k_pre_node3<<<dim3(46,20),256,0,stream>>>(naP, p2p, m2g, m2bt,
      m3W1, m3b1, m3W2, m3b2, g3b, p3p);
  k_bnred<<<20,256,0,stream>>>(p3p, 46, 1.f/11776.f, m3g, m3bt, scsh3);
  k_wbs<<<2112,256,0,stream>>>(pmW, psW, emW, esW, Wbs);
  k_wbt<<<2880,256,0,stream>>>(pmW, psW, emW, esW, scsh3, Wbt);
  k_cst<<<15,256,0,stream>>>(pmW, psW, emW, esW, scsh3, cst);

  // ---- 2-kernel software-pipelined scan ----
  for (int t=0;t<=11;t++){
    int nh = (t<10)?32:0;
    int ne = (t>=1 && t<=10)?512:0;
    int nd = (t>=2)?352:0;
    int tt  = (t<10)? t : 0;
    int tm1 = (t>=1)? t-1 : 0;
    int tm2 = (t>=2)? t-2 : 0;
    float* rcur  = (t&1)? raw1 : raw0;
    float* rprev = (t&1)? raw0 : raw1;
    if (nh+ne+nd > 0)
      k_KA<<<nh+ne+nd,256,0,stream>>>(nh, ne, tt,
          g3b, hbf, Wbt, Wbs, cst, rcur,
          rprev, eps + (size_t)tm1*47104,
          pmB, psB, emB, esB, zp1,
          m1W1+64, m1b1+16, m1W2+128, m1b2+16, m1g+16, m1bt+16,
          m2W1+288, m2b1+16, m2W2+128, m2b2+16,
          zna, zp2, lklp + (size_t)tm1*512,
          zg3, zp3, m3g+16, m3bt+16, dmW, dmB, dsW, dsB,
          out + (size_t)tm2*45056, out + 450560 + (size_t)tm2*45056);
    int ng = (t<10)?368:0;
    int nn = (t>=1 && t<=10)?46:0;
    if (ng+nn > 0)
      k_KB<<<ng+nn,256,0,stream>>>(ng,
          h, hbf, states + (size_t)((t<10)? t+1 : 1)*47104,
          rcur, eps + (size_t)tt*47104,
          emB, esB, m1W1+64, m1b1+16, m1W2+128, m1b2+16, zp1,
          gWih, gWhh, gbih, gbhh,
          zna, zp2, m2g+16, m2bt+16,
          m3W1+160, m3b1+16, m3W2+128, m3b2+16, zg3, zp3);
  }
  k_final<<<1,256,0,stream>>>(lklp, out + 901120);
}